// Round 2
// baseline (477.733 us; speedup 1.0000x reference)
//
#include <hip/hip_runtime.h>
#include <hip/hip_bf16.h>

#define N_NODES 10000
#define N_EDGES 320000
#define D 256

// ---------- edge counting sort ----------
__global__ void hist_kernel(const int* __restrict__ dst, int* __restrict__ cnt) {
  int e = blockIdx.x * blockDim.x + threadIdx.x;
  if (e < N_EDGES) atomicAdd(&cnt[dst[e]], 1);
}

__global__ __launch_bounds__(1024) void scan_kernel(const int* __restrict__ cnt,
                                                    int* __restrict__ offs,
                                                    int* __restrict__ cursors, int n) {
  __shared__ int buf[1024];
  __shared__ int carry_s;
  const int t = threadIdx.x;
  if (t == 0) carry_s = 0;
  __syncthreads();
  for (int base = 0; base < n; base += 1024) {
    int i = base + t;
    int v = (i < n) ? cnt[i] : 0;
    buf[t] = v;
    __syncthreads();
    for (int off = 1; off < 1024; off <<= 1) {
      int x = (t >= off) ? buf[t - off] : 0;
      __syncthreads();
      buf[t] += x;
      __syncthreads();
    }
    int total = buf[1023];
    int excl = buf[t] - v;
    int carry = carry_s;
    if (i < n) { offs[i] = carry + excl; cursors[i] = carry + excl; }
    __syncthreads();
    if (t == 0) carry_s = carry + total;
    __syncthreads();
  }
  if (t == 0) offs[n] = carry_s;
}

__global__ void fill_kernel(const int* __restrict__ dst, int* __restrict__ cursors,
                            int* __restrict__ eids) {
  int e = blockIdx.x * blockDim.x + threadIdx.x;
  if (e < N_EDGES) {
    int pos = atomicAdd(&cursors[dst[e]], 1);
    eids[pos] = e;
  }
}

// ---------- aggregation: one wave per destination node ----------
__global__ __launch_bounds__(256) void agg_kernel(const int* __restrict__ offs,
                                                  const int* __restrict__ eids,
                                                  const int* __restrict__ src,
                                                  const int* __restrict__ rel,
                                                  const float* __restrict__ Mbuf,
                                                  float* __restrict__ agg) {
  int node = blockIdx.x * 4 + (threadIdx.x >> 6);
  int lane = threadIdx.x & 63;
  if (node >= N_NODES) return;
  float4 acc = make_float4(0.f, 0.f, 0.f, 0.f);
  int beg = offs[node], end = offs[node + 1];
  for (int j = beg; j < end; ++j) {
    int e = eids[j];
    int s = src[e];
    int r = rel[e];
    const float4* row = (const float4*)(Mbuf + ((size_t)r * N_NODES + s) * D);
    float4 v = row[lane];
    acc.x += v.x; acc.y += v.y; acc.z += v.z; acc.w += v.w;
  }
  ((float4*)(agg + (size_t)node * D))[lane] = acc;
}

// ---------- generic tiled GEMM: C[M,N] = act(A[M,K] @ W[N,K]^T + b (+ b2)) ----------
// 64x64 block tile, 256 threads, 4x4 microtile, k-chunk 16, fp32 accumulate.
template<bool RELU>
__global__ __launch_bounds__(256) void gemm_kernel(
    const float* __restrict__ A, const float* __restrict__ W,
    const float* __restrict__ bias, const float* __restrict__ bias2,
    float* __restrict__ C, int M, int N, int K)
{
  __shared__ float As[16][68];   // [kk][row]
  __shared__ float Bs[16][68];   // [kk][col] = W[col][k0+kk]
  const int t  = threadIdx.x;
  const int tx = t & 15, ty = t >> 4;
  const int m0 = blockIdx.y * 64, n0 = blockIdx.x * 64;
  const int lr = t >> 2;            // 0..63
  const int lk = (t & 3) << 2;      // 0,4,8,12
  int am = m0 + lr; if (am > M - 1) am = M - 1;   // clamp (stores are guarded)
  const int wn = n0 + lr;                         // N is always a multiple of 64 here

  float acc[4][4] = {};

  for (int k0 = 0; k0 < K; k0 += 16) {
    {
      float4 v = *(const float4*)(A + (size_t)am * K + k0 + lk);
      As[lk + 0][lr] = v.x; As[lk + 1][lr] = v.y;
      As[lk + 2][lr] = v.z; As[lk + 3][lr] = v.w;
    }
    {
      float4 v = *(const float4*)(W + (size_t)wn * K + k0 + lk);
      Bs[lk + 0][lr] = v.x; Bs[lk + 1][lr] = v.y;
      Bs[lk + 2][lr] = v.z; Bs[lk + 3][lr] = v.w;
    }
    __syncthreads();
#pragma unroll
    for (int kk = 0; kk < 16; ++kk) {
      float4 a = *(const float4*)&As[kk][ty << 2];
      float4 b = *(const float4*)&Bs[kk][tx << 2];
      acc[0][0] += a.x * b.x; acc[0][1] += a.x * b.y; acc[0][2] += a.x * b.z; acc[0][3] += a.x * b.w;
      acc[1][0] += a.y * b.x; acc[1][1] += a.y * b.y; acc[1][2] += a.y * b.z; acc[1][3] += a.y * b.w;
      acc[2][0] += a.z * b.x; acc[2][1] += a.z * b.y; acc[2][2] += a.z * b.z; acc[2][3] += a.z * b.w;
      acc[3][0] += a.w * b.x; acc[3][1] += a.w * b.y; acc[3][2] += a.w * b.z; acc[3][3] += a.w * b.w;
    }
    __syncthreads();
  }

#pragma unroll
  for (int i = 0; i < 4; ++i) {
    int m = m0 + (ty << 2) + i;
    if (m >= M) continue;
#pragma unroll
    for (int j = 0; j < 4; ++j) {
      int n = n0 + (tx << 2) + j;
      float c = acc[i][j] + bias[n];
      if (bias2) c += bias2[n];
      if constexpr (RELU) c = fmaxf(c, 0.f);
      C[(size_t)m * N + n] = c;
    }
  }
}

// ---------- LSTM single-step elementwise ----------
__global__ void lstm_kernel(const float* __restrict__ gates, float* __restrict__ hn) {
  int j = blockIdx.x * blockDim.x + threadIdx.x;
  if (j >= N_NODES * D) return;
  int n = j >> 8, d = j & 255;
  const float* g = gates + (size_t)n * 1024;
  float vi = g[d], vg = g[512 + d], vo = g[768 + d];
  float si = 1.f / (1.f + __expf(-vi));
  float so = 1.f / (1.f + __expf(-vo));
  float c = si * tanhf(vg);
  hn[j] = so * tanhf(c);
}

// ---------- launch ----------
extern "C" void kernel_launch(void* const* d_in, const int* in_sizes, int n_in,
                              void* d_out, int out_size, void* d_ws, size_t ws_size,
                              hipStream_t stream) {
  const float* feat  = (const float*)d_in[0];
  const int* src = (const int*)d_in[1];
  const int* dst = (const int*)d_in[2];
  const int* rel = (const int*)d_in[3];
  const float* W_rel = (const float*)d_in[4];
  const float* b_rel = (const float*)d_in[5];
  const float* W_ih  = (const float*)d_in[6];
  const float* b_ih  = (const float*)d_in[7];
  const float* b_hh  = (const float*)d_in[8];
  const float* W1 = (const float*)d_in[9];
  const float* b1 = (const float*)d_in[10];
  const float* W2 = (const float*)d_in[11];
  const float* b2 = (const float*)d_in[12];
  const float* W3 = (const float*)d_in[13];
  const float* b3 = (const float*)d_in[14];
  float* out = (float*)d_out;

  char* ws = (char*)d_ws;
  // Phase 1 layout:  H [0,20.48M)  M [20.48M,40.96M)  agg [40.96M,51.2M)
  // Phase 2 overlay: gates [0,40.96M)  hn [40.96M,51.2M)  x1 [0,5.12M)  x2 [5.12M,10.24M)
  float* Hbuf  = (float*)(ws);
  float* Mbuf  = (float*)(ws + 20480000);
  float* aggb  = (float*)(ws + 40960000);
  float* gates = (float*)(ws);
  float* hn    = (float*)(ws + 40960000);
  float* x1    = (float*)(ws);
  float* x2    = (float*)(ws + 5120000);
  const size_t SB = 51200000;   // sort scratch
  int* cnt     = (int*)(ws + SB);
  int* offs    = (int*)(ws + SB + 40000);
  int* cursors = (int*)(ws + SB + 80016);
  int* eids    = (int*)(ws + SB + 120016);

  // edge counting sort by dst (independent of GEMMs, stream-ordered)
  (void)hipMemsetAsync(cnt, 0, N_NODES * sizeof(int), stream);
  hist_kernel<<<(N_EDGES + 255) / 256, 256, 0, stream>>>(dst, cnt);
  scan_kernel<<<1, 1024, 0, stream>>>(cnt, offs, cursors, N_NODES);
  fill_kernel<<<(N_EDGES + 255) / 256, 256, 0, stream>>>(dst, cursors, eids);

  const dim3 blk(256);
  const int MB = (N_NODES + 63) / 64;   // 157

  // edge NN layer 1: H_r = relu(feat @ W_r^T + b_r)
  gemm_kernel<true><<<dim3(4, MB), blk, 0, stream>>>(
      feat, W_rel, b_rel, nullptr, Hbuf, N_NODES, 256, 256);
  gemm_kernel<true><<<dim3(4, MB), blk, 0, stream>>>(
      feat, W_rel + 65536, b_rel + 256, nullptr, Hbuf + 2560000, N_NODES, 256, 256);
  // edge NN layer 2 (tied weights): M_r = relu(H_r @ W_r^T + b_r)
  gemm_kernel<true><<<dim3(4, MB), blk, 0, stream>>>(
      Hbuf, W_rel, b_rel, nullptr, Mbuf, N_NODES, 256, 256);
  gemm_kernel<true><<<dim3(4, MB), blk, 0, stream>>>(
      Hbuf + 2560000, W_rel + 65536, b_rel + 256, nullptr, Mbuf + 2560000, N_NODES, 256, 256);

  // scatter-sum via sorted gather: agg[v] = sum over edges e with dst==v of M[rel[e]][src[e]]
  agg_kernel<<<2500, 256, 0, stream>>>(offs, eids, src, rel, Mbuf, aggb);

  // LSTM gates = agg @ W_ih^T + b_ih + b_hh   (N=1024)
  gemm_kernel<false><<<dim3(16, MB), blk, 0, stream>>>(
      aggb, W_ih, b_ih, b_hh, gates, N_NODES, 1024, 256);
  lstm_kernel<<<(N_NODES * D + 255) / 256, 256, 0, stream>>>(gates, hn);

  // global MLP
  gemm_kernel<true><<<dim3(2, MB), blk, 0, stream>>>(
      hn, W1, b1, nullptr, x1, N_NODES, 128, 256);
  gemm_kernel<true><<<dim3(2, MB), blk, 0, stream>>>(
      x1, W2, b2, nullptr, x2, N_NODES, 128, 128);
  gemm_kernel<false><<<dim3(4, MB), blk, 0, stream>>>(
      x2, W3, b3, nullptr, out, N_NODES, 256, 128);
}

// Round 3
// 288.050 us; speedup vs baseline: 1.6585x; 1.6585x over previous
//
#include <hip/hip_runtime.h>
#include <hip/hip_bf16.h>

#define N_NODES 10000
#define N_EDGES 320000
#define D 256

typedef __attribute__((ext_vector_type(8))) short bf16x8;
typedef __attribute__((ext_vector_type(4))) float f32x4;

__device__ __forceinline__ float bf2f(unsigned short u) {
  union { unsigned int i; float f; } x; x.i = ((unsigned int)u) << 16; return x.f;
}
__device__ __forceinline__ unsigned short f2bf(float f) {
  union { float f; unsigned int i; } x; x.f = f;
  unsigned int lsb = (x.i >> 16) & 1u;
  x.i += 0x7fffu + lsb;            // round-to-nearest-even
  return (unsigned short)(x.i >> 16);
}

__device__ __forceinline__ void async_copy16(const void* g, void* l) {
  __builtin_amdgcn_global_load_lds(
      (const __attribute__((address_space(1))) unsigned int*)g,
      (__attribute__((address_space(3))) unsigned int*)l, 16, 0, 0);
}

// ---------- prep: cast weights/feat to bf16, pack i/g/o gate weights ----------
__global__ void prep_kernel(const float* __restrict__ feat, const float* __restrict__ W_rel,
                            const float* __restrict__ W_ih, const float* __restrict__ b_ih,
                            const float* __restrict__ b_hh, const float* __restrict__ W1,
                            const float* __restrict__ W2, const float* __restrict__ W3,
                            unsigned short* featb, unsigned short* W_relb,
                            unsigned short* Wg, float* bg,
                            unsigned short* W1b, unsigned short* W2b, unsigned short* W3b) {
  int i = blockIdx.x * 256 + threadIdx.x;
  if (i < 2560000) { featb[i] = f2bf(feat[i]); return; }
  i -= 2560000;
  if (i < 131072) { W_relb[i] = f2bf(W_rel[i]); return; }
  i -= 131072;
  if (i < 196608) {           // W_ih rows {0-255 (i), 512-767 (g), 768-1023 (o)}
    int n = i >> 8, k = i & 255;
    int m = (n < 256) ? n : n + 256;
    Wg[i] = f2bf(W_ih[m * 256 + k]); return;
  }
  i -= 196608;
  if (i < 32768) { W1b[i] = f2bf(W1[i]); return; }
  i -= 32768;
  if (i < 16384) { W2b[i] = f2bf(W2[i]); return; }
  i -= 16384;
  if (i < 32768) { W3b[i] = f2bf(W3[i]); return; }
  i -= 32768;
  if (i < 768) { int m = (i < 256) ? i : i + 256; bg[i] = b_ih[m] + b_hh[m]; }
}

// ---------- edge counting sort ----------
__global__ void hist_kernel(const int* __restrict__ dst, int* __restrict__ cnt) {
  int e = blockIdx.x * blockDim.x + threadIdx.x;
  if (e < N_EDGES) atomicAdd(&cnt[dst[e]], 1);
}

__global__ __launch_bounds__(1024) void scan_kernel(const int* __restrict__ cnt,
                                                    int* __restrict__ offs,
                                                    int* __restrict__ cursors, int n) {
  __shared__ int buf[1024];
  __shared__ int carry_s;
  const int t = threadIdx.x;
  if (t == 0) carry_s = 0;
  __syncthreads();
  for (int base = 0; base < n; base += 1024) {
    int i = base + t;
    int v = (i < n) ? cnt[i] : 0;
    buf[t] = v;
    __syncthreads();
    for (int off = 1; off < 1024; off <<= 1) {
      int x = (t >= off) ? buf[t - off] : 0;
      __syncthreads();
      buf[t] += x;
      __syncthreads();
    }
    int total = buf[1023];
    int excl = buf[t] - v;
    int carry = carry_s;
    if (i < n) { offs[i] = carry + excl; cursors[i] = carry + excl; }
    __syncthreads();
    if (t == 0) carry_s = carry + total;
    __syncthreads();
  }
  if (t == 0) offs[n] = carry_s;
}

// fill: rowoff[pos] = element offset of M row for this edge (rel,src)
__global__ void fill_kernel(const int* __restrict__ dst, const int* __restrict__ src,
                            const int* __restrict__ rel, int* __restrict__ cursors,
                            unsigned int* __restrict__ rowoff) {
  int e = blockIdx.x * blockDim.x + threadIdx.x;
  if (e < N_EDGES) {
    int pos = atomicAdd(&cursors[dst[e]], 1);
    rowoff[pos] = (unsigned int)((rel[e] * N_NODES + src[e]) * D);
  }
}

// ---------- aggregation: one wave per destination node, bf16 rows, fp32 accumulate ----------
__global__ __launch_bounds__(256) void agg_kernel(const int* __restrict__ offs,
                                                  const unsigned int* __restrict__ rowoff,
                                                  const unsigned short* __restrict__ Mb,
                                                  unsigned short* __restrict__ aggb) {
  int node = blockIdx.x * 4 + (threadIdx.x >> 6);
  int lane = threadIdx.x & 63;
  if (node >= N_NODES) return;
  float a0 = 0.f, a1 = 0.f, a2 = 0.f, a3 = 0.f;
  int beg = offs[node], end = offs[node + 1];
  unsigned int off = (beg < end) ? rowoff[beg] : 0u;
  for (int j = beg; j < end; ++j) {
    unsigned int offn = (j + 1 < end) ? rowoff[j + 1] : 0u;
    ushort4 v = *(const ushort4*)(Mb + (size_t)off + lane * 4);
    a0 += bf2f(v.x); a1 += bf2f(v.y); a2 += bf2f(v.z); a3 += bf2f(v.w);
    off = offn;
  }
  ushort4 o;
  o.x = f2bf(a0); o.y = f2bf(a1); o.z = f2bf(a2); o.w = f2bf(a3);
  *(ushort4*)(aggb + (size_t)node * D + lane * 4) = o;
}

// ---------- MFMA GEMM: C[z][M][N] = act(A[z][M][K](bf16) @ W[z][N][K](bf16)^T + bias) ----------
// 128x128 tile, BK=32, 256 threads = 4 waves (2x2 of 64x64), 4x4 MFMA 16x16x32 tiles/wave.
// LDS quad-swizzle: slot(row,q) holds global quad q ^ ((row>>1)&3) -> 2-way-free ds_read_b128.
template<bool RELU, bool OUTF32>
__global__ __launch_bounds__(256) void mfma_gemm(
    const unsigned short* __restrict__ A, const unsigned short* __restrict__ W,
    const float* __restrict__ bias, void* __restrict__ Cout,
    int M, int N, int K, long aZ, long wZ, long bZ, long cZ)
{
  __shared__ alignas(16) unsigned short As[128 * 32];
  __shared__ alignas(16) unsigned short Bs[128 * 32];
  const int t = threadIdx.x;
  const int wave = t >> 6, lane = t & 63;
  const int z = blockIdx.z;
  const int m0 = blockIdx.y * 128, n0 = blockIdx.x * 128;
  const unsigned short* Ab = A + (size_t)z * aZ;
  const unsigned short* Wb = W + (size_t)z * wZ;
  const float* bb = bias + (size_t)z * bZ;

  const int wm = (wave >> 1) * 64, wn = (wave & 1) * 64;
  const int lrow = lane & 15, quad = lane >> 4;

  f32x4 acc[4][4];
#pragma unroll
  for (int i = 0; i < 4; ++i)
#pragma unroll
    for (int j = 0; j < 4; ++j) acc[i][j] = (f32x4)0.0f;

  // staging geometry (per thread, loop-invariant)
  const int sr_loc = lane >> 2;      // row within 16-row issue group
  const int sslot  = lane & 3;       // 16B slot within row

  for (int k0 = 0; k0 < K; k0 += 32) {
#pragma unroll
    for (int s = 0; s < 2; ++s) {
      int t8 = wave + 4 * s;                 // issue 0..7
      int r  = t8 * 16 + sr_loc;             // tile row 0..127
      int gq = sslot ^ ((r >> 1) & 3);       // global quad to fetch
      int gr = m0 + r; if (gr > M - 1) gr = M - 1;
      async_copy16(Ab + (size_t)gr * K + k0 + gq * 8, As + t8 * 512);
      int gn = n0 + r;                       // N is a multiple of 128
      async_copy16(Wb + (size_t)gn * K + k0 + gq * 8, Bs + t8 * 512);
    }
    __syncthreads();

    bf16x8 af[4], bfr[4];
#pragma unroll
    for (int i = 0; i < 4; ++i) {
      int r = wm + i * 16 + lrow;
      int sl = quad ^ ((r >> 1) & 3);
      af[i] = *(const bf16x8*)(As + r * 32 + sl * 8);
    }
#pragma unroll
    for (int j = 0; j < 4; ++j) {
      int r = wn + j * 16 + lrow;
      int sl = quad ^ ((r >> 1) & 3);
      bfr[j] = *(const bf16x8*)(Bs + r * 32 + sl * 8);
    }
#pragma unroll
    for (int i = 0; i < 4; ++i)
#pragma unroll
      for (int j = 0; j < 4; ++j)
        acc[i][j] = __builtin_amdgcn_mfma_f32_16x16x32_bf16(af[i], bfr[j], acc[i][j], 0, 0, 0);
    __syncthreads();
  }

  // epilogue: C/D layout col=lane&15, row=quad*4+reg
#pragma unroll
  for (int i = 0; i < 4; ++i) {
    int rbase = m0 + wm + i * 16 + quad * 4;
#pragma unroll
    for (int j = 0; j < 4; ++j) {
      int col = n0 + wn + j * 16 + lrow;
      float bv = bb[col];
#pragma unroll
      for (int reg = 0; reg < 4; ++reg) {
        int gm = rbase + reg;
        if (gm < M) {
          float c = acc[i][j][reg] + bv;
          if constexpr (RELU) c = fmaxf(c, 0.f);
          if constexpr (OUTF32) ((float*)Cout)[(size_t)z * cZ + (size_t)gm * N + col] = c;
          else ((unsigned short*)Cout)[(size_t)z * cZ + (size_t)gm * N + col] = f2bf(c);
        }
      }
    }
  }
}

// ---------- LSTM single-step elementwise (i,g,o packed; f*c0==0) ----------
__global__ void lstm_kernel(const unsigned short* __restrict__ gatesb,
                            unsigned short* __restrict__ hnb) {
  int n = blockIdx.x, d = threadIdx.x;
  const unsigned short* g = gatesb + (size_t)n * 768;
  float vi = bf2f(g[d]), vg = bf2f(g[256 + d]), vo = bf2f(g[512 + d]);
  float si = 1.f / (1.f + __expf(-vi));
  float so = 1.f / (1.f + __expf(-vo));
  float c = si * tanhf(vg);
  hnb[(size_t)n * D + d] = f2bf(so * tanhf(c));
}

// ---------- launch ----------
extern "C" void kernel_launch(void* const* d_in, const int* in_sizes, int n_in,
                              void* d_out, int out_size, void* d_ws, size_t ws_size,
                              hipStream_t stream) {
  const float* feat  = (const float*)d_in[0];
  const int* src = (const int*)d_in[1];
  const int* dst = (const int*)d_in[2];
  const int* rel = (const int*)d_in[3];
  const float* W_rel = (const float*)d_in[4];
  const float* b_rel = (const float*)d_in[5];
  const float* W_ih  = (const float*)d_in[6];
  const float* b_ih  = (const float*)d_in[7];
  const float* b_hh  = (const float*)d_in[8];
  const float* W1 = (const float*)d_in[9];
  const float* b1 = (const float*)d_in[10];
  const float* W2 = (const float*)d_in[11];
  const float* b2 = (const float*)d_in[12];
  const float* W3 = (const float*)d_in[13];
  const float* b3 = (const float*)d_in[14];
  float* out = (float*)d_out;

  char* ws = (char*)d_ws;
  // activations (with overlays; all offsets bytes)
  unsigned short* featb  = (unsigned short*)(ws);              // 5,120,000
  unsigned short* Hb     = (unsigned short*)(ws + 5120000);    // 10,240,000 (2 slabs)
  unsigned short* Mb     = (unsigned short*)(ws + 15360000);   // 10,240,000 (2 slabs)
  unsigned short* aggb   = (unsigned short*)(ws + 25600000);   // 5,120,000
  unsigned short* gatesb = (unsigned short*)(ws);              // 15,360,000 overlay featb+Hb (dead)
  unsigned short* hnb    = (unsigned short*)(ws + 15360000);   // 5,120,000 overlay Mb (dead)
  unsigned short* x1b    = (unsigned short*)(ws + 20480000);   // 2,560,000
  unsigned short* x2b    = (unsigned short*)(ws + 23040000);   // 2,560,000
  // weights + sort scratch
  char* wsb = ws + 30720000;
  unsigned short* W_relb = (unsigned short*)(wsb);             // 262,144
  unsigned short* Wg     = (unsigned short*)(wsb + 262400);    // 393,216
  unsigned short* W1b    = (unsigned short*)(wsb + 655872);    // 65,536
  unsigned short* W2b    = (unsigned short*)(wsb + 721664);    // 32,768
  unsigned short* W3b    = (unsigned short*)(wsb + 754688);    // 65,536
  float*          bg     = (float*)(wsb + 820480);             // 3,072
  int*            cnt    = (int*)(wsb + 823808);               // 40,000
  int*            offs   = (int*)(wsb + 864000);               // 40,004
  int*            cursors= (int*)(wsb + 904192);               // 40,000
  unsigned int*   rowoff = (unsigned int*)(wsb + 944384);      // 1,280,000

  // prep casts (2,970,368 elems)
  prep_kernel<<<11603, 256, 0, stream>>>(feat, W_rel, W_ih, b_ih, b_hh, W1, W2, W3,
                                         featb, W_relb, Wg, bg, W1b, W2b, W3b);
  // edge counting sort by dst
  (void)hipMemsetAsync(cnt, 0, N_NODES * sizeof(int), stream);
  hist_kernel<<<1250, 256, 0, stream>>>(dst, cnt);
  scan_kernel<<<1, 1024, 0, stream>>>(cnt, offs, cursors, N_NODES);
  fill_kernel<<<1250, 256, 0, stream>>>(dst, src, rel, cursors, rowoff);

  const int MB = (N_NODES + 127) / 128;  // 79

  // edge NN layer 1 (both relations via z): H_r = relu(feat @ W_r^T + b_r)
  mfma_gemm<true, false><<<dim3(2, MB, 2), 256, 0, stream>>>(
      featb, W_relb, b_rel, Hb, N_NODES, 256, 256, 0, 65536, 256, 2560000);
  // edge NN layer 2 (tied weights): M_r = relu(H_r @ W_r^T + b_r)
  mfma_gemm<true, false><<<dim3(2, MB, 2), 256, 0, stream>>>(
      Hb, W_relb, b_rel, Mb, N_NODES, 256, 256, 2560000, 65536, 256, 2560000);

  // scatter-sum via sorted gather
  agg_kernel<<<2500, 256, 0, stream>>>(offs, rowoff, Mb, aggb);

  // gates (i,g,o only) = agg @ Wg^T + bg
  mfma_gemm<false, false><<<dim3(6, MB, 1), 256, 0, stream>>>(
      aggb, Wg, bg, gatesb, N_NODES, 768, 256, 0, 0, 0, 0);
  lstm_kernel<<<N_NODES, 256, 0, stream>>>(gatesb, hnb);

  // global MLP
  mfma_gemm<true, false><<<dim3(1, MB, 1), 256, 0, stream>>>(
      hnb, W1b, b1, x1b, N_NODES, 128, 256, 0, 0, 0, 0);
  mfma_gemm<true, false><<<dim3(1, MB, 1), 256, 0, stream>>>(
      x1b, W2b, b2, x2b, N_NODES, 128, 128, 0, 0, 0, 0);
  mfma_gemm<false, true><<<dim3(2, MB, 1), 256, 0, stream>>>(
      x2b, W3b, b3, out, N_NODES, 256, 128, 0, 0, 0, 0);
}

// Round 4
// 263.926 us; speedup vs baseline: 1.8101x; 1.0914x over previous
//
#include <hip/hip_runtime.h>
#include <hip/hip_bf16.h>

#define N_NODES 10000
#define N_EDGES 320000
#define D 256

typedef __attribute__((ext_vector_type(8))) _Float16 f16x8;
typedef __attribute__((ext_vector_type(4))) _Float16 f16x4;
typedef __attribute__((ext_vector_type(4))) float f32x4;

__device__ __forceinline__ void async_copy16(const void* g, void* l) {
  __builtin_amdgcn_global_load_lds(
      (const __attribute__((address_space(1))) unsigned int*)g,
      (__attribute__((address_space(3))) unsigned int*)l, 16, 0, 0);
}

// ---------- prep: cast weights/feat to fp16, pack i/g/o gate weights, edge histogram ----------
__global__ void prep_kernel(const float* __restrict__ feat, const float* __restrict__ W_rel,
                            const float* __restrict__ W_ih, const float* __restrict__ b_ih,
                            const float* __restrict__ b_hh, const float* __restrict__ W1,
                            const float* __restrict__ W2, const float* __restrict__ W3,
                            const int* __restrict__ dst, int* __restrict__ cnt,
                            _Float16* feath, _Float16* W_relh,
                            _Float16* Wg, float* bg,
                            _Float16* W1h, _Float16* W2h, _Float16* W3h) {
  int i = blockIdx.x * 256 + threadIdx.x;
  if (i < N_EDGES) { atomicAdd(&cnt[dst[i]], 1); return; }
  i -= N_EDGES;
  if (i < 2560000) { feath[i] = (_Float16)feat[i]; return; }
  i -= 2560000;
  if (i < 131072) { W_relh[i] = (_Float16)W_rel[i]; return; }
  i -= 131072;
  if (i < 196608) {           // W_ih rows {0-255 (i), 512-767 (g), 768-1023 (o)}
    int n = i >> 8, k = i & 255;
    int m = (n < 256) ? n : n + 256;
    Wg[i] = (_Float16)W_ih[m * 256 + k]; return;
  }
  i -= 196608;
  if (i < 32768) { W1h[i] = (_Float16)W1[i]; return; }
  i -= 32768;
  if (i < 16384) { W2h[i] = (_Float16)W2[i]; return; }
  i -= 16384;
  if (i < 32768) { W3h[i] = (_Float16)W3[i]; return; }
  i -= 32768;
  if (i < 768) { int m = (i < 256) ? i : i + 256; bg[i] = b_ih[m] + b_hh[m]; }
}

// ---------- scan: 1024 threads, 10 elems/thread sequential + one LDS scan ----------
__global__ __launch_bounds__(1024) void scan_kernel(const int* __restrict__ cnt,
                                                    int* __restrict__ offs,
                                                    int* __restrict__ cursors, int n) {
  __shared__ int buf[1024];
  const int t = threadIdx.x;
  int loc[10];
  int s = 0;
  int base = t * 10;
#pragma unroll
  for (int q = 0; q < 10; ++q) {
    int i = base + q;
    int v = (i < n) ? cnt[i] : 0;
    loc[q] = s;            // exclusive within thread
    s += v;
  }
  buf[t] = s;
  __syncthreads();
  for (int off = 1; off < 1024; off <<= 1) {
    int x = (t >= off) ? buf[t - off] : 0;
    __syncthreads();
    buf[t] += x;
    __syncthreads();
  }
  int excl = buf[t] - s;    // exclusive prefix of this thread's chunk
#pragma unroll
  for (int q = 0; q < 10; ++q) {
    int i = base + q;
    if (i < n) { int o = excl + loc[q]; offs[i] = o; cursors[i] = o; }
  }
  if (t == 1023) offs[n] = buf[1023];
}

// fill: rowoff[pos] = element offset of M row for this edge (rel,src)
__global__ void fill_kernel(const int* __restrict__ dst, const int* __restrict__ src,
                            const int* __restrict__ rel, int* __restrict__ cursors,
                            unsigned int* __restrict__ rowoff) {
  int e = blockIdx.x * blockDim.x + threadIdx.x;
  if (e < N_EDGES) {
    int pos = atomicAdd(&cursors[dst[e]], 1);
    rowoff[pos] = (unsigned int)((rel[e] * N_NODES + src[e]) * D);
  }
}

// ---------- aggregation: one block (4 waves) per node; waves split edges; LDS reduce ----------
__global__ __launch_bounds__(256) void agg_kernel(const int* __restrict__ offs,
                                                  const unsigned int* __restrict__ rowoff,
                                                  const _Float16* __restrict__ Mh,
                                                  _Float16* __restrict__ aggh) {
  __shared__ float part[4][256];
  const int node = blockIdx.x;
  const int wave = threadIdx.x >> 6, lane = threadIdx.x & 63;
  float a0 = 0.f, a1 = 0.f, a2 = 0.f, a3 = 0.f;
  const int beg = offs[node], end = offs[node + 1];
  for (int j = beg + wave; j < end; j += 4) {
    unsigned int off = rowoff[j];
    f16x4 v = *(const f16x4*)(Mh + (size_t)off + lane * 4);
    a0 += (float)v[0]; a1 += (float)v[1]; a2 += (float)v[2]; a3 += (float)v[3];
  }
  *(float4*)&part[wave][lane * 4] = make_float4(a0, a1, a2, a3);
  __syncthreads();
  if (wave == 0) {
    float4 p0 = *(const float4*)&part[0][lane * 4];
    float4 p1 = *(const float4*)&part[1][lane * 4];
    float4 p2 = *(const float4*)&part[2][lane * 4];
    float4 p3 = *(const float4*)&part[3][lane * 4];
    f16x4 o;
    o[0] = (_Float16)(p0.x + p1.x + p2.x + p3.x);
    o[1] = (_Float16)(p0.y + p1.y + p2.y + p3.y);
    o[2] = (_Float16)(p0.z + p1.z + p2.z + p3.z);
    o[3] = (_Float16)(p0.w + p1.w + p2.w + p3.w);
    *(f16x4*)(aggh + (size_t)node * D + lane * 4) = o;
  }
}

// ---------- MFMA GEMM: C[z][M][N] = act(A[z][M][K](f16) @ W[z][N][K](f16)^T + bias) ----------
// 128x128 tile, BK=32, 256 threads = 4 waves (2x2 of 64x64), 4x4 MFMA 16x16x32 tiles/wave.
// LDS quad-swizzle: slot(row,q) holds global quad q ^ ((row>>1)&3) -> 2-way-free ds_read_b128.
template<bool RELU, bool OUTF32>
__global__ __launch_bounds__(256) void mfma_gemm(
    const _Float16* __restrict__ A, const _Float16* __restrict__ W,
    const float* __restrict__ bias, void* __restrict__ Cout,
    int M, int N, int K, long aZ, long wZ, long bZ, long cZ)
{
  __shared__ alignas(16) _Float16 As[128 * 32];
  __shared__ alignas(16) _Float16 Bs[128 * 32];
  const int t = threadIdx.x;
  const int wave = t >> 6, lane = t & 63;
  const int z = blockIdx.z;
  const int m0 = blockIdx.y * 128, n0 = blockIdx.x * 128;
  const _Float16* Ab = A + (size_t)z * aZ;
  const _Float16* Wb = W + (size_t)z * wZ;
  const float* bb = bias + (size_t)z * bZ;

  const int wm = (wave >> 1) * 64, wn = (wave & 1) * 64;
  const int lrow = lane & 15, quad = lane >> 4;

  f32x4 acc[4][4];
#pragma unroll
  for (int i = 0; i < 4; ++i)
#pragma unroll
    for (int j = 0; j < 4; ++j) acc[i][j] = (f32x4)0.0f;

  const int sr_loc = lane >> 2;      // row within 16-row issue group
  const int sslot  = lane & 3;       // 16B slot within row

  for (int k0 = 0; k0 < K; k0 += 32) {
#pragma unroll
    for (int s = 0; s < 2; ++s) {
      int t8 = wave + 4 * s;                 // issue 0..7
      int r  = t8 * 16 + sr_loc;             // tile row 0..127
      int gq = sslot ^ ((r >> 1) & 3);       // global quad to fetch
      int gr = m0 + r; if (gr > M - 1) gr = M - 1;
      async_copy16(Ab + (size_t)gr * K + k0 + gq * 8, As + t8 * 512);
      int gn = n0 + r;                       // N is a multiple of 128
      async_copy16(Wb + (size_t)gn * K + k0 + gq * 8, Bs + t8 * 512);
    }
    __syncthreads();

    f16x8 af[4], bfr[4];
#pragma unroll
    for (int i = 0; i < 4; ++i) {
      int r = wm + i * 16 + lrow;
      int sl = quad ^ ((r >> 1) & 3);
      af[i] = *(const f16x8*)(As + r * 32 + sl * 8);
    }
#pragma unroll
    for (int j = 0; j < 4; ++j) {
      int r = wn + j * 16 + lrow;
      int sl = quad ^ ((r >> 1) & 3);
      bfr[j] = *(const f16x8*)(Bs + r * 32 + sl * 8);
    }
#pragma unroll
    for (int i = 0; i < 4; ++i)
#pragma unroll
      for (int j = 0; j < 4; ++j)
        acc[i][j] = __builtin_amdgcn_mfma_f32_16x16x32_f16(af[i], bfr[j], acc[i][j], 0, 0, 0);
    __syncthreads();
  }

  // epilogue: C/D layout col=lane&15, row=quad*4+reg
#pragma unroll
  for (int i = 0; i < 4; ++i) {
    int rbase = m0 + wm + i * 16 + quad * 4;
#pragma unroll
    for (int j = 0; j < 4; ++j) {
      int col = n0 + wn + j * 16 + lrow;
      float bv = bb[col];
#pragma unroll
      for (int reg = 0; reg < 4; ++reg) {
        int gm = rbase + reg;
        if (gm < M) {
          float c = acc[i][j][reg] + bv;
          if constexpr (RELU) c = fmaxf(c, 0.f);
          if constexpr (OUTF32) ((float*)Cout)[(size_t)z * cZ + (size_t)gm * N + col] = c;
          else ((_Float16*)Cout)[(size_t)z * cZ + (size_t)gm * N + col] = (_Float16)c;
        }
      }
    }
  }
}

// ---------- LSTM single-step elementwise (i,g,o packed; f*c0==0) ----------
__global__ void lstm_kernel(const _Float16* __restrict__ gatesh,
                            _Float16* __restrict__ hnh) {
  int n = blockIdx.x, d = threadIdx.x;
  const _Float16* g = gatesh + (size_t)n * 768;
  float vi = (float)g[d], vg = (float)g[256 + d], vo = (float)g[512 + d];
  float si = 1.f / (1.f + __expf(-vi));
  float so = 1.f / (1.f + __expf(-vo));
  float c = si * tanhf(vg);
  hnh[(size_t)n * D + d] = (_Float16)(so * tanhf(c));
}

// ---------- launch ----------
extern "C" void kernel_launch(void* const* d_in, const int* in_sizes, int n_in,
                              void* d_out, int out_size, void* d_ws, size_t ws_size,
                              hipStream_t stream) {
  const float* feat  = (const float*)d_in[0];
  const int* src = (const int*)d_in[1];
  const int* dst = (const int*)d_in[2];
  const int* rel = (const int*)d_in[3];
  const float* W_rel = (const float*)d_in[4];
  const float* b_rel = (const float*)d_in[5];
  const float* W_ih  = (const float*)d_in[6];
  const float* b_ih  = (const float*)d_in[7];
  const float* b_hh  = (const float*)d_in[8];
  const float* W1 = (const float*)d_in[9];
  const float* b1 = (const float*)d_in[10];
  const float* W2 = (const float*)d_in[11];
  const float* b2 = (const float*)d_in[12];
  const float* W3 = (const float*)d_in[13];
  const float* b3 = (const float*)d_in[14];
  float* out = (float*)d_out;

  char* ws = (char*)d_ws;
  // activations (with overlays; all offsets bytes)
  _Float16* feath  = (_Float16*)(ws);              // 5,120,000
  _Float16* Hh     = (_Float16*)(ws + 5120000);    // 10,240,000 (2 slabs)
  _Float16* Mh     = (_Float16*)(ws + 15360000);   // 10,240,000 (2 slabs)
  _Float16* aggh   = (_Float16*)(ws + 25600000);   // 5,120,000
  _Float16* gatesh = (_Float16*)(ws);              // 15,360,000 overlay feath+Hh (dead)
  _Float16* hnh    = (_Float16*)(ws + 15360000);   // 5,120,000 overlay Mh (dead)
  _Float16* x1h    = (_Float16*)(ws + 20480000);   // 2,560,000
  _Float16* x2h    = (_Float16*)(ws + 23040000);   // 2,560,000
  // weights + sort scratch
  char* wsb = ws + 30720000;
  _Float16* W_relh = (_Float16*)(wsb);             // 262,144
  _Float16* Wg     = (_Float16*)(wsb + 262400);    // 393,216
  _Float16* W1h    = (_Float16*)(wsb + 655872);    // 65,536
  _Float16* W2h    = (_Float16*)(wsb + 721664);    // 32,768
  _Float16* W3h    = (_Float16*)(wsb + 754688);    // 65,536
  float*    bg     = (float*)(wsb + 820480);       // 3,072
  int*      cnt    = (int*)(wsb + 823808);         // 40,000
  int*      offs   = (int*)(wsb + 864000);         // 40,004
  int*      cursors= (int*)(wsb + 904192);         // 40,000
  unsigned int* rowoff = (unsigned int*)(wsb + 944384);  // 1,280,000

  // prep casts + edge histogram (320,000 + 2,970,368 = 3,290,368 elems)
  (void)hipMemsetAsync(cnt, 0, N_NODES * sizeof(int), stream);
  prep_kernel<<<12853, 256, 0, stream>>>(feat, W_rel, W_ih, b_ih, b_hh, W1, W2, W3,
                                         dst, cnt, feath, W_relh, Wg, bg, W1h, W2h, W3h);
  scan_kernel<<<1, 1024, 0, stream>>>(cnt, offs, cursors, N_NODES);
  fill_kernel<<<1250, 256, 0, stream>>>(dst, src, rel, cursors, rowoff);

  const int MB = (N_NODES + 127) / 128;  // 79

  // edge NN layer 1 (both relations via z): H_r = relu(feat @ W_r^T + b_r)
  mfma_gemm<true, false><<<dim3(2, MB, 2), 256, 0, stream>>>(
      feath, W_relh, b_rel, Hh, N_NODES, 256, 256, 0, 65536, 256, 2560000);
  // edge NN layer 2 (tied weights): M_r = relu(H_r @ W_r^T + b_r)
  mfma_gemm<true, false><<<dim3(2, MB, 2), 256, 0, stream>>>(
      Hh, W_relh, b_rel, Mh, N_NODES, 256, 256, 2560000, 65536, 256, 2560000);

  // scatter-sum via sorted gather
  agg_kernel<<<N_NODES, 256, 0, stream>>>(offs, rowoff, Mh, aggh);

  // gates (i,g,o only) = agg @ Wg^T + bg
  mfma_gemm<false, false><<<dim3(6, MB, 1), 256, 0, stream>>>(
      aggh, Wg, bg, gatesh, N_NODES, 768, 256, 0, 0, 0, 0);
  lstm_kernel<<<N_NODES, 256, 0, stream>>>(gatesh, hnh);

  // global MLP
  mfma_gemm<true, false><<<dim3(1, MB, 1), 256, 0, stream>>>(
      hnh, W1h, b1, x1h, N_NODES, 128, 256, 0, 0, 0, 0);
  mfma_gemm<true, false><<<dim3(1, MB, 1), 256, 0, stream>>>(
      x1h, W2h, b2, x2h, N_NODES, 128, 128, 0, 0, 0, 0);
  mfma_gemm<false, true><<<dim3(2, MB, 1), 256, 0, stream>>>(
      x2h, W3h, b3, out, N_NODES, 256, 128, 0, 0, 0, 0);
}